// Round 5
// baseline (421.465 us; speedup 1.0000x reference)
//
#include <hip/hip_runtime.h>

#define BATCH 4
#define SEQ   1024
#define EMB   256
#define NH    12
#define EH    3072   // EMB*NH
#define MROWS 4096   // BATCH*SEQ

typedef __attribute__((ext_vector_type(8))) short bf16x8;
typedef __attribute__((ext_vector_type(4))) float f32x4;
typedef __attribute__((ext_vector_type(4))) short short4v;

__device__ __forceinline__ short f2bf(float f) {
  union { float f; unsigned u; } x; x.f = f;
  unsigned r = x.u + 0x7fffu + ((x.u >> 16) & 1u);  // round-to-nearest-even
  return (short)(r >> 16);
}

__device__ __forceinline__ void gload_lds16(const void* g, void* l) {
  __builtin_amdgcn_global_load_lds(
      (const __attribute__((address_space(1))) unsigned*)g,
      (__attribute__((address_space(3))) unsigned*)l, 16, 0, 0);
}

// ---------------- cast x (fp32 -> bf16) ----------------
__global__ __launch_bounds__(256) void cast_x_kernel(const float* __restrict__ in,
                                                     short* __restrict__ out) {
  int i = (blockIdx.x * 256 + threadIdx.x) * 4;
  float4 v = *(const float4*)(in + i);
  short4v o;
  o[0] = f2bf(v.x); o[1] = f2bf(v.y); o[2] = f2bf(v.z); o[3] = f2bf(v.w);
  *(short4v*)(out + i) = o;
}

// ------- transpose + cast, fused QKV: z selects Wq/Wk/Wv (all [EMB][EH]) -------
__global__ __launch_bounds__(256) void transpose_qkv_kernel(const float* __restrict__ Wq,
                                                            const float* __restrict__ Wk,
                                                            const float* __restrict__ Wv,
                                                            short* __restrict__ Wt) {
  __shared__ float tile[32][33];
  const float* W = blockIdx.z == 0 ? Wq : (blockIdx.z == 1 ? Wk : Wv);
  short* o = Wt + (size_t)blockIdx.z * EH * EMB;
  const int n0 = blockIdx.x * 32, k0 = blockIdx.y * 32;
  const int tx = threadIdx.x & 31, ty = threadIdx.x >> 5;  // 32 x 8
#pragma unroll
  for (int i = 0; i < 4; i++)
    tile[ty + 8 * i][tx] = W[(size_t)(k0 + ty + 8 * i) * EH + n0 + tx];
  __syncthreads();
#pragma unroll
  for (int i = 0; i < 4; i++) {
    int nr = ty + 8 * i;
    o[(size_t)(n0 + nr) * EMB + k0 + tx] = f2bf(tile[tx][nr]);
  }
}

// ---------------- generic transpose + cast W[K][N] -> Wt[N][K] ----------------
__global__ __launch_bounds__(256) void transpose_cast_kernel(const float* __restrict__ W,
                                                             short* __restrict__ Wt,
                                                             int K, int N) {
  __shared__ float tile[32][33];
  const int n0 = blockIdx.x * 32, k0 = blockIdx.y * 32;
  const int tx = threadIdx.x & 31, ty = threadIdx.x >> 5;
#pragma unroll
  for (int i = 0; i < 4; i++)
    tile[ty + 8 * i][tx] = W[(size_t)(k0 + ty + 8 * i) * N + n0 + tx];
  __syncthreads();
#pragma unroll
  for (int i = 0; i < 4; i++) {
    int nr = ty + 8 * i;
    Wt[(size_t)(n0 + nr) * K + k0 + tx] = f2bf(tile[tx][nr]);
  }
}

// ------- fused QKV GEMM: C[4096][9216] = xb * WqkvT^T, region epilogues -------
// region 0: q row-major; region 1: k row-major; region 2: v -> [b][h][d][s].
__global__ __launch_bounds__(256) void qkv_gemm_kernel(const short* __restrict__ A,
                                                       const short* __restrict__ Bt,
                                                       const float* __restrict__ bq,
                                                       const float* __restrict__ bk,
                                                       const float* __restrict__ bv,
                                                       short* __restrict__ qout,
                                                       short* __restrict__ kout,
                                                       short* __restrict__ vout) {
  constexpr int BM = 128, BN = 128, BK = 32, K = EMB;
  constexpr int WM = 64, WN = 64, MT = 4, NT = 4;
  __shared__ short As[BM * BK];
  __shared__ short Bs[BN * BK];
  const int tid = threadIdx.x;
  const int w = tid >> 6, lane = tid & 63;
  const int wm = w >> 1, wn = w & 1;
  const int l15 = lane & 15, l4 = lane >> 4;
  const int m0 = blockIdx.x * BM, n0 = blockIdx.y * BN;

  f32x4 acc[MT][NT] = {};
  const int crow = lane >> 2;
  const int ckb  = (lane & 3) * 16;

  for (int k0 = 0; k0 < K; k0 += BK) {
#pragma unroll
    for (int i = 0; i < 2; i++) {
      int c = w + i * 4;
      gload_lds16((const char*)(A + (size_t)(m0 + c * 16 + crow) * K + k0) + ckb,
                  (char*)As + c * 1024);
      gload_lds16((const char*)(Bt + (size_t)(n0 + c * 16 + crow) * K + k0) + ckb,
                  (char*)Bs + c * 1024);
    }
    asm volatile("s_waitcnt vmcnt(0)" ::: "memory");
    __syncthreads();

    bf16x8 af[MT], bfr[NT];
#pragma unroll
    for (int mt = 0; mt < MT; mt++)
      af[mt] = *(const bf16x8*)&As[(wm * WM + mt * 16 + l15) * BK + 8 * l4];
#pragma unroll
    for (int nt = 0; nt < NT; nt++)
      bfr[nt] = *(const bf16x8*)&Bs[(wn * WN + nt * 16 + l15) * BK + 8 * l4];
#pragma unroll
    for (int mt = 0; mt < MT; mt++)
#pragma unroll
      for (int nt = 0; nt < NT; nt++)
        acc[mt][nt] = __builtin_amdgcn_mfma_f32_16x16x32_bf16(af[mt], bfr[nt], acc[mt][nt], 0, 0, 0);
    __syncthreads();
  }

  const int region = n0 / 3072;  // block-uniform (3072 % 128 == 0)
  const float* bias = region == 0 ? bq : (region == 1 ? bk : bv);
#pragma unroll
  for (int nt = 0; nt < NT; nt++) {
    const int n = n0 + wn * WN + nt * 16 + l15;
    const int col = n - region * 3072;
    const float bvv = bias[col];
#pragma unroll
    for (int mt = 0; mt < MT; mt++) {
      const int mrow = m0 + wm * WM + mt * 16 + 4 * l4;
      f32x4 v = acc[mt][nt];
      if (region < 2) {
        short* C = region == 0 ? qout : kout;
#pragma unroll
        for (int r = 0; r < 4; r++)
          C[(size_t)(mrow + r) * EH + col] = f2bf(v[r] + bvv);
      } else {
        const int bb = mrow >> 10;
        const int s  = mrow & 1023;
        const int h  = col >> 8, d = col & 255;
        short4v o4;
        o4[0] = f2bf(v[0] + bvv); o4[1] = f2bf(v[1] + bvv);
        o4[2] = f2bf(v[2] + bvv); o4[3] = f2bf(v[3] + bvv);
        *(short4v*)&vout[((size_t)(bb * NH + h) * EMB + d) * SEQ + s] = o4;
      }
    }
  }
}

// ---------------- fc GEMM: out[M][N] = ctx * WfcT^T + bias (fp32 out) ----------------
__global__ __launch_bounds__(256) void fc_gemm_kernel(const short* __restrict__ A,
                                                      const short* __restrict__ Bt,
                                                      const float* __restrict__ bias,
                                                      float* __restrict__ Cout,
                                                      int M, int N, int K) {
  constexpr int BM = 64, BN = 64, BK = 32;
  constexpr int WM = 32, WN = 32, MT = 2, NT = 2;
  __shared__ short As[BM * BK];
  __shared__ short Bs[BN * BK];
  const int tid = threadIdx.x;
  const int w = tid >> 6, lane = tid & 63;
  const int wm = w >> 1, wn = w & 1;
  const int l15 = lane & 15, l4 = lane >> 4;
  const int m0 = blockIdx.x * BM, n0 = blockIdx.y * BN;

  f32x4 acc[MT][NT] = {};
  const int crow = lane >> 2;
  const int ckb  = (lane & 3) * 16;

  for (int k0 = 0; k0 < K; k0 += BK) {
    {
      int c = w;
      gload_lds16((const char*)(A + (size_t)(m0 + c * 16 + crow) * K + k0) + ckb,
                  (char*)As + c * 1024);
      gload_lds16((const char*)(Bt + (size_t)(n0 + c * 16 + crow) * K + k0) + ckb,
                  (char*)Bs + c * 1024);
    }
    asm volatile("s_waitcnt vmcnt(0)" ::: "memory");
    __syncthreads();

    bf16x8 af[MT], bfr[NT];
#pragma unroll
    for (int mt = 0; mt < MT; mt++)
      af[mt] = *(const bf16x8*)&As[(wm * WM + mt * 16 + l15) * BK + 8 * l4];
#pragma unroll
    for (int nt = 0; nt < NT; nt++)
      bfr[nt] = *(const bf16x8*)&Bs[(wn * WN + nt * 16 + l15) * BK + 8 * l4];
#pragma unroll
    for (int mt = 0; mt < MT; mt++)
#pragma unroll
      for (int nt = 0; nt < NT; nt++)
        acc[mt][nt] = __builtin_amdgcn_mfma_f32_16x16x32_bf16(af[mt], bfr[nt], acc[mt][nt], 0, 0, 0);
    __syncthreads();
  }

#pragma unroll
  for (int nt = 0; nt < NT; nt++) {
    const int n = n0 + wn * WN + nt * 16 + l15;
    const float bvv = bias[n];
#pragma unroll
    for (int mt = 0; mt < MT; mt++) {
      const int mrow = m0 + wm * WM + mt * 16 + 4 * l4;
      f32x4 v = acc[mt][nt];
#pragma unroll
      for (int r = 0; r < 4; r++)
        Cout[(size_t)(mrow + r) * N + n] = v[r] + bvv;
    }
  }
}

// ---------------- causal flash attention ----------------
// grid (BATCH*NH, SEQ/64), q-tile = 15 - blockIdx.y (heavy-first packing).
// K staged in LDS (T14 async reg-stage), V read DIRECT from global (L2-fit,
// m169), P per-wave LDS. Softmax in log2 domain + T13 defer-rescale.
// LDS = 40 KB -> 3-4 blocks/CU.
__global__ __launch_bounds__(256, 3) void attn_kernel(const short* __restrict__ Q,
                                                      const short* __restrict__ Kg,
                                                      const short* __restrict__ Vt,
                                                      short* __restrict__ Ctx) {
  __shared__ short Ks[64 * 256];    // [kv][d], rows swizzled
  __shared__ short Ps[4 * 16 * 64]; // per-wave P tile [q][kv], swizzled
  const int tid = threadIdx.x, w = tid >> 6, lane = tid & 63;
  const int l15 = lane & 15, l4 = lane >> 4;
  const int bh = blockIdx.x, b = bh / NH, h = bh % NH;
  const int qt = (gridDim.y - 1) - blockIdx.y;   // heavy-first
  const int q0 = qt * 64;
  const int ntiles = qt + 1;

  // scale folded with log2(e); mask in log2 domain (names avoid HIP macro MASK2)
  const float kScaleL2 = 0.0625f * 1.4426950408889634f;
  const float kMaskL2  = -14426.95f;
  const float kThrL2   = 11.5f;   // ~= 8 nats (HK defer threshold)

  bf16x8 qf[8];
  {
    const short* qp = Q + (size_t)(b * SEQ + q0 + w * 16 + l15) * EH + h * EMB + 8 * l4;
#pragma unroll
    for (int kst = 0; kst < 8; kst++) qf[kst] = *(const bf16x8*)(qp + 32 * kst);
  }

  const short* Kbase = Kg + (size_t)b * SEQ * EH + h * EMB;
  const short* Vbase = Vt + (size_t)bh * EMB * SEQ;

  bf16x8 kreg[8];
  // ---- prologue: stage K tile 0 ----
#pragma unroll
  for (int it = 0; it < 8; it++) {
    int c = it * 256 + tid;
    int row = c >> 5, e = (c & 31) * 8;
    kreg[it] = *(const bf16x8*)(Kbase + (size_t)row * EH + e);
  }
#pragma unroll
  for (int it = 0; it < 8; it++) {
    int c = it * 256 + tid;
    int row = c >> 5, e = (c & 31) * 8;
    *(bf16x8*)&Ks[row * 256 + (e ^ ((row & 7) << 3))] = kreg[it];
  }
  __syncthreads();

  f32x4 o[16] = {};
  float mst[4], lst[4];
#pragma unroll
  for (int r = 0; r < 4; r++) { mst[r] = -1e30f; lst[r] = 0.f; }

  for (int t = 0; t < ntiles; t++) {
    const int kv0 = t * 64;
    const bool pf = (t + 1 < ntiles);   // block-uniform

    // ---- issue next-tile K loads (hide HBM latency under QK+softmax) ----
    if (pf) {
      const short* kp = Kbase + (size_t)(kv0 + 64) * EH;
#pragma unroll
      for (int it = 0; it < 8; it++) {
        int c = it * 256 + tid;
        int row = c >> 5, e = (c & 31) * 8;
        kreg[it] = *(const bf16x8*)(kp + (size_t)row * EH + e);
      }
    }

    // ---- S = Q K^T ----
    f32x4 sf[4] = {};
    __builtin_amdgcn_s_setprio(1);
#pragma unroll
    for (int nt = 0; nt < 4; nt++) {
      const int krw = nt * 16 + l15;
#pragma unroll
      for (int kst = 0; kst < 8; kst++) {
        bf16x8 kf = *(const bf16x8*)&Ks[krw * 256 + ((kst * 32 + 8 * l4) ^ ((krw & 7) << 3))];
        sf[nt] = __builtin_amdgcn_mfma_f32_16x16x32_bf16(qf[kst], kf, sf[nt], 0, 0, 0);
      }
    }
    __builtin_amdgcn_s_setprio(0);

    // ---- online softmax, log2 domain, defer-rescale ----
    float pp[4][4];
    float fsc[4];
    bool skip[4];
#pragma unroll
    for (int r = 0; r < 4; r++) {
      const int qrow = q0 + w * 16 + 4 * l4 + r;
      float sc[4];
      float mx = -1e30f;
#pragma unroll
      for (int nt = 0; nt < 4; nt++) {
        int kvg = kv0 + nt * 16 + l15;
        float s = sf[nt][r] * kScaleL2 + (kvg > qrow ? kMaskL2 : 0.0f);
        sc[nt] = s;
        mx = fmaxf(mx, s);
      }
      mx = fmaxf(mx, __shfl_xor(mx, 1));
      mx = fmaxf(mx, __shfl_xor(mx, 2));
      mx = fmaxf(mx, __shfl_xor(mx, 4));
      mx = fmaxf(mx, __shfl_xor(mx, 8));
      skip[r] = __all(mx <= mst[r] + kThrL2);
      float mref;
      if (skip[r]) {
        fsc[r] = 1.0f;
        mref = mst[r];
      } else {
        float mnew = fmaxf(mst[r], mx);
        fsc[r] = exp2f(mst[r] - mnew);
        mst[r] = mnew;
        mref = mnew;
      }
      float rs = 0.f;
#pragma unroll
      for (int nt = 0; nt < 4; nt++) {
        float e = exp2f(sc[nt] - mref);
        pp[nt][r] = e;
        rs += e;
      }
      rs += __shfl_xor(rs, 1);
      rs += __shfl_xor(rs, 2);
      rs += __shfl_xor(rs, 4);
      rs += __shfl_xor(rs, 8);
      lst[r] = lst[r] * fsc[r] + rs;
    }
#pragma unroll
    for (int r = 0; r < 4; r++) {
      if (!skip[r]) {
#pragma unroll
        for (int nt = 0; nt < 16; nt++) o[nt][r] *= fsc[r];
      }
    }

    // ---- P -> per-wave LDS (A-fragment source) ----
#pragma unroll
    for (int nt = 0; nt < 4; nt++)
#pragma unroll
      for (int r = 0; r < 4; r++) {
        int prow = 4 * l4 + r;
        Ps[w * 1024 + prow * 64 + ((l15 + 16 * nt) ^ ((prow & 7) << 3))] = f2bf(pp[nt][r]);
      }
    __syncthreads();   // all waves done reading Ks tile t

    // ---- write next K tile into Ks (overlaps PV) ----
    if (pf) {
#pragma unroll
      for (int it = 0; it < 8; it++) {
        int c = it * 256 + tid;
        int row = c >> 5, e = (c & 31) * 8;
        *(bf16x8*)&Ks[row * 256 + (e ^ ((row & 7) << 3))] = kreg[it];
      }
    }

    // ---- O += P V  (V fragments direct from global; L2-resident) ----
    __builtin_amdgcn_s_setprio(1);
#pragma unroll
    for (int kst = 0; kst < 2; kst++) {
      bf16x8 af = *(const bf16x8*)&Ps[w * 1024 + l15 * 64 + ((kst * 32 + 8 * l4) ^ ((l15 & 7) << 3))];
#pragma unroll
      for (int nt = 0; nt < 16; nt++) {
        const int vrw = nt * 16 + l15;
        bf16x8 vf = *(const bf16x8*)(Vbase + (size_t)vrw * SEQ + kv0 + kst * 32 + 8 * l4);
        o[nt] = __builtin_amdgcn_mfma_f32_16x16x32_bf16(af, vf, o[nt], 0, 0, 0);
      }
    }
    __builtin_amdgcn_s_setprio(0);
    __syncthreads();   // Ks writes visible before next QK
  }

  // ---- normalize + store ctx (bf16, merged [m][h*256+d]) ----
  float inv[4];
#pragma unroll
  for (int r = 0; r < 4; r++) inv[r] = 1.f / lst[r];
  const int mrow = b * SEQ + q0 + w * 16 + 4 * l4;
#pragma unroll
  for (int nt = 0; nt < 16; nt++) {
    const int d = h * EMB + nt * 16 + l15;
#pragma unroll
    for (int r = 0; r < 4; r++)
      Ctx[(size_t)(mrow + r) * EH + d] = f2bf(o[nt][r] * inv[r]);
  }
}

extern "C" void kernel_launch(void* const* d_in, const int* in_sizes, int n_in,
                              void* d_out, int out_size, void* d_ws, size_t ws_size,
                              hipStream_t stream) {
  const float* x   = (const float*)d_in[0];
  const float* Wq  = (const float*)d_in[2];
  const float* bq  = (const float*)d_in[3];
  const float* Wk  = (const float*)d_in[4];
  const float* bk  = (const float*)d_in[5];
  const float* Wv  = (const float*)d_in[6];
  const float* bv  = (const float*)d_in[7];
  const float* Wfc = (const float*)d_in[8];
  const float* bfc = (const float*)d_in[9];
  float* out = (float*)d_out;

  short* ws    = (short*)d_ws;
  short* xb    = ws;                  // 4096*256
  short* wqkvt = xb + 1048576;        // 3*3072*256 contiguous [9216][256]
  short* wfct  = wqkvt + 3 * 786432;  // 256*3072
  short* q     = wfct + 786432;       // 4096*3072
  short* k     = q + 12582912;
  short* vt    = k + 12582912;        // [b][h][d][s]
  short* ctx   = vt + 12582912;       // 4096*3072

  cast_x_kernel<<<1024, 256, 0, stream>>>(x, xb);
  transpose_qkv_kernel<<<dim3(EH / 32, EMB / 32, 3), 256, 0, stream>>>(Wq, Wk, Wv, wqkvt);
  transpose_cast_kernel<<<dim3(EMB / 32, EH / 32), 256, 0, stream>>>(Wfc, wfct, EH, EMB);

  qkv_gemm_kernel<<<dim3(MROWS / 128, 9216 / 128), 256, 0, stream>>>(
      xb, wqkvt, bq, bk, bv, q, k, vt);

  attn_kernel<<<dim3(BATCH * NH, SEQ / 64), 256, 0, stream>>>(q, k, vt, ctx);

  fc_gemm_kernel<<<dim3(MROWS / 64, EMB / 64), 256, 0, stream>>>(ctx, wfct, bfc, out, MROWS, EMB, EH);
}

// Round 6
// 196.357 us; speedup vs baseline: 2.1464x; 2.1464x over previous
//
#include <hip/hip_runtime.h>

#define BATCH 4
#define SEQ   1024
#define EMB   256
#define NH    12
#define EH    3072   // EMB*NH
#define MROWS 4096   // BATCH*SEQ

typedef __attribute__((ext_vector_type(8))) short bf16x8;
typedef __attribute__((ext_vector_type(4))) float f32x4;
typedef __attribute__((ext_vector_type(4))) short short4v;

__device__ __forceinline__ short f2bf(float f) {
  union { float f; unsigned u; } x; x.f = f;
  unsigned r = x.u + 0x7fffu + ((x.u >> 16) & 1u);  // round-to-nearest-even
  return (short)(r >> 16);
}

__device__ __forceinline__ void gload_lds16(const void* g, void* l) {
  __builtin_amdgcn_global_load_lds(
      (const __attribute__((address_space(1))) unsigned*)g,
      (__attribute__((address_space(3))) unsigned*)l, 16, 0, 0);
}

// ---------------- cast x (fp32 -> bf16) ----------------
__global__ __launch_bounds__(256) void cast_x_kernel(const float* __restrict__ in,
                                                     short* __restrict__ out) {
  int i = (blockIdx.x * 256 + threadIdx.x) * 4;
  float4 v = *(const float4*)(in + i);
  short4v o;
  o[0] = f2bf(v.x); o[1] = f2bf(v.y); o[2] = f2bf(v.z); o[3] = f2bf(v.w);
  *(short4v*)(out + i) = o;
}

// ------- transpose + cast, fused QKV: z selects Wq/Wk/Wv (all [EMB][EH]) -------
__global__ __launch_bounds__(256) void transpose_qkv_kernel(const float* __restrict__ Wq,
                                                            const float* __restrict__ Wk,
                                                            const float* __restrict__ Wv,
                                                            short* __restrict__ Wt) {
  __shared__ float tile[32][33];
  const float* W = blockIdx.z == 0 ? Wq : (blockIdx.z == 1 ? Wk : Wv);
  short* o = Wt + (size_t)blockIdx.z * EH * EMB;
  const int n0 = blockIdx.x * 32, k0 = blockIdx.y * 32;
  const int tx = threadIdx.x & 31, ty = threadIdx.x >> 5;  // 32 x 8
#pragma unroll
  for (int i = 0; i < 4; i++)
    tile[ty + 8 * i][tx] = W[(size_t)(k0 + ty + 8 * i) * EH + n0 + tx];
  __syncthreads();
#pragma unroll
  for (int i = 0; i < 4; i++) {
    int nr = ty + 8 * i;
    o[(size_t)(n0 + nr) * EMB + k0 + tx] = f2bf(tile[tx][nr]);
  }
}

// ---------------- generic transpose + cast W[K][N] -> Wt[N][K] ----------------
__global__ __launch_bounds__(256) void transpose_cast_kernel(const float* __restrict__ W,
                                                             short* __restrict__ Wt,
                                                             int K, int N) {
  __shared__ float tile[32][33];
  const int n0 = blockIdx.x * 32, k0 = blockIdx.y * 32;
  const int tx = threadIdx.x & 31, ty = threadIdx.x >> 5;
#pragma unroll
  for (int i = 0; i < 4; i++)
    tile[ty + 8 * i][tx] = W[(size_t)(k0 + ty + 8 * i) * N + n0 + tx];
  __syncthreads();
#pragma unroll
  for (int i = 0; i < 4; i++) {
    int nr = ty + 8 * i;
    Wt[(size_t)(n0 + nr) * K + k0 + tx] = f2bf(tile[tx][nr]);
  }
}

// ------- fused QKV GEMM: C[4096][9216] = xb * WqkvT^T, region epilogues -------
// region 0: q row-major, PRE-SCALED by log2(e)/16; region 1: k row-major;
// region 2: v -> [b][h][d][s].
__global__ __launch_bounds__(256) void qkv_gemm_kernel(const short* __restrict__ A,
                                                       const short* __restrict__ Bt,
                                                       const float* __restrict__ bq,
                                                       const float* __restrict__ bk,
                                                       const float* __restrict__ bv,
                                                       short* __restrict__ qout,
                                                       short* __restrict__ kout,
                                                       short* __restrict__ vout) {
  constexpr int BM = 128, BN = 128, BK = 32, K = EMB;
  constexpr int WM = 64, WN = 64, MT = 4, NT = 4;
  __shared__ short As[BM * BK];
  __shared__ short Bs[BN * BK];
  const int tid = threadIdx.x;
  const int w = tid >> 6, lane = tid & 63;
  const int wm = w >> 1, wn = w & 1;
  const int l15 = lane & 15, l4 = lane >> 4;
  const int m0 = blockIdx.x * BM, n0 = blockIdx.y * BN;

  f32x4 acc[MT][NT] = {};
  const int crow = lane >> 2;
  const int ckb  = (lane & 3) * 16;

  for (int k0 = 0; k0 < K; k0 += BK) {
#pragma unroll
    for (int i = 0; i < 2; i++) {
      int c = w + i * 4;
      gload_lds16((const char*)(A + (size_t)(m0 + c * 16 + crow) * K + k0) + ckb,
                  (char*)As + c * 1024);
      gload_lds16((const char*)(Bt + (size_t)(n0 + c * 16 + crow) * K + k0) + ckb,
                  (char*)Bs + c * 1024);
    }
    asm volatile("s_waitcnt vmcnt(0)" ::: "memory");
    __syncthreads();

    bf16x8 af[MT], bfr[NT];
#pragma unroll
    for (int mt = 0; mt < MT; mt++)
      af[mt] = *(const bf16x8*)&As[(wm * WM + mt * 16 + l15) * BK + 8 * l4];
#pragma unroll
    for (int nt = 0; nt < NT; nt++)
      bfr[nt] = *(const bf16x8*)&Bs[(wn * WN + nt * 16 + l15) * BK + 8 * l4];
#pragma unroll
    for (int mt = 0; mt < MT; mt++)
#pragma unroll
      for (int nt = 0; nt < NT; nt++)
        acc[mt][nt] = __builtin_amdgcn_mfma_f32_16x16x32_bf16(af[mt], bfr[nt], acc[mt][nt], 0, 0, 0);
    __syncthreads();
  }

  const int region = n0 / 3072;  // block-uniform (3072 % 128 == 0)
  const float* bias = region == 0 ? bq : (region == 1 ? bk : bv);
  const float kQScale = 0.09016844f;  // (1/16) * log2(e), folded into Q
#pragma unroll
  for (int nt = 0; nt < NT; nt++) {
    const int n = n0 + wn * WN + nt * 16 + l15;
    const int col = n - region * 3072;
    const float bvv = bias[col];
#pragma unroll
    for (int mt = 0; mt < MT; mt++) {
      const int mrow = m0 + wm * WM + mt * 16 + 4 * l4;
      f32x4 v = acc[mt][nt];
      if (region == 0) {
#pragma unroll
        for (int r = 0; r < 4; r++)
          qout[(size_t)(mrow + r) * EH + col] = f2bf((v[r] + bvv) * kQScale);
      } else if (region == 1) {
#pragma unroll
        for (int r = 0; r < 4; r++)
          kout[(size_t)(mrow + r) * EH + col] = f2bf(v[r] + bvv);
      } else {
        const int bb = mrow >> 10;
        const int s  = mrow & 1023;
        const int h  = col >> 8, d = col & 255;
        short4v o4;
        o4[0] = f2bf(v[0] + bvv); o4[1] = f2bf(v[1] + bvv);
        o4[2] = f2bf(v[2] + bvv); o4[3] = f2bf(v[3] + bvv);
        *(short4v*)&vout[((size_t)(bb * NH + h) * EMB + d) * SEQ + s] = o4;
      }
    }
  }
}

// ---------------- fc GEMM: out[M][N] = ctx * WfcT^T + bias (fp32 out) ----------------
__global__ __launch_bounds__(256) void fc_gemm_kernel(const short* __restrict__ A,
                                                      const short* __restrict__ Bt,
                                                      const float* __restrict__ bias,
                                                      float* __restrict__ Cout,
                                                      int M, int N, int K) {
  constexpr int BM = 64, BN = 64, BK = 32;
  constexpr int WM = 32, WN = 32, MT = 2, NT = 2;
  __shared__ short As[BM * BK];
  __shared__ short Bs[BN * BK];
  const int tid = threadIdx.x;
  const int w = tid >> 6, lane = tid & 63;
  const int wm = w >> 1, wn = w & 1;
  const int l15 = lane & 15, l4 = lane >> 4;
  const int m0 = blockIdx.x * BM, n0 = blockIdx.y * BN;

  f32x4 acc[MT][NT] = {};
  const int crow = lane >> 2;
  const int ckb  = (lane & 3) * 16;

  for (int k0 = 0; k0 < K; k0 += BK) {
    {
      int c = w;
      gload_lds16((const char*)(A + (size_t)(m0 + c * 16 + crow) * K + k0) + ckb,
                  (char*)As + c * 1024);
      gload_lds16((const char*)(Bt + (size_t)(n0 + c * 16 + crow) * K + k0) + ckb,
                  (char*)Bs + c * 1024);
    }
    asm volatile("s_waitcnt vmcnt(0)" ::: "memory");
    __syncthreads();

    bf16x8 af[MT], bfr[NT];
#pragma unroll
    for (int mt = 0; mt < MT; mt++)
      af[mt] = *(const bf16x8*)&As[(wm * WM + mt * 16 + l15) * BK + 8 * l4];
#pragma unroll
    for (int nt = 0; nt < NT; nt++)
      bfr[nt] = *(const bf16x8*)&Bs[(wn * WN + nt * 16 + l15) * BK + 8 * l4];
#pragma unroll
    for (int mt = 0; mt < MT; mt++)
#pragma unroll
      for (int nt = 0; nt < NT; nt++)
        acc[mt][nt] = __builtin_amdgcn_mfma_f32_16x16x32_bf16(af[mt], bfr[nt], acc[mt][nt], 0, 0, 0);
    __syncthreads();
  }

#pragma unroll
  for (int nt = 0; nt < NT; nt++) {
    const int n = n0 + wn * WN + nt * 16 + l15;
    const float bvv = bias[n];
#pragma unroll
    for (int mt = 0; mt < MT; mt++) {
      const int mrow = m0 + wm * WM + mt * 16 + 4 * l4;
      f32x4 v = acc[mt][nt];
#pragma unroll
      for (int r = 0; r < 4; r++)
        Cout[(size_t)(mrow + r) * N + n] = v[r] + bvv;
    }
  }
}

// ---------------- causal flash attention (m97-style staging) ----------------
// grid (BATCH*NH, SEQ/64), q-tile = 15 - blockIdx.y (heavy-first packing).
// KVBLK = 32. LDS 36 KB: Ks [8 kst][32 kv][32 d] + Vs [256 d][32 kv] + per-wave
// Ps [16][32]. Staged via global_load_lds (linear LDS, fragment-ordered so all
// ds_read_b128 are contiguous-1KB conflict-free). No reg prefetch -> VGPR ~145
// -> 3 blocks/CU; cross-block overlap hides staging latency (m114).
// Q is pre-scaled by log2(e)/16; softmax in exp2 domain, defer-rescale,
// distributed l-state, mask only on the 2 diagonal tiles.
__global__ __launch_bounds__(256) void attn_kernel(const short* __restrict__ Q,
                                                   const short* __restrict__ Kg,
                                                   const short* __restrict__ Vt,
                                                   short* __restrict__ Ctx) {
  __shared__ short Ks[8 * 32 * 32];   // 16 KB
  __shared__ short Vs[256 * 32];      // 16 KB
  __shared__ short Ps[4 * 16 * 32];   // 4 KB, per-wave
  const int tid = threadIdx.x, w = tid >> 6, lane = tid & 63;
  const int l15 = lane & 15, l4 = lane >> 4;
  const int bh = blockIdx.x, b = bh / NH, h = bh % NH;
  const int qt = (gridDim.y - 1) - blockIdx.y;   // heavy-first
  const int q0 = qt * 64;
  const int ntiles = 2 * qt + 2;

  const float kMaskL2 = -14426.95f;   // -10000 * log2(e)
  const float kThrL2  = 11.5f;        // ~8 nats defer threshold

  bf16x8 qf[8];
  {
    const short* qp = Q + (size_t)(b * SEQ + q0 + w * 16 + l15) * EH + h * EMB + 8 * l4;
#pragma unroll
    for (int kst = 0; kst < 8; kst++) qf[kst] = *(const bf16x8*)(qp + 32 * kst);
  }

  const short* Kbase = Kg + (size_t)b * SEQ * EH + h * EMB;
  const short* Vbase = Vt + (size_t)bh * EMB * SEQ;

  // staging lane geometry: each chunk = 16 rows x 64B, lane covers 16B
  const int srow = lane >> 2;        // row within chunk
  const int s16  = (lane & 3) * 8;   // short offset within 64B row piece

  f32x4 o[16] = {};
  float mst[4], lst[4];
#pragma unroll
  for (int r = 0; r < 4; r++) { mst[r] = -1e30f; lst[r] = 0.f; }

  for (int t = 0; t < ntiles; t++) {
    const int kv0 = t * 32;

    // ---- stage K (as [kst][kv][32d]) and V ([d][kv]) via global_load_lds ----
#pragma unroll
    for (int i = 0; i < 4; i++) {
      const int c = w * 4 + i;  // chunk 0..15
      // K chunk: kst = c>>1, kv half = c&1
      gload_lds16(Kbase + (size_t)(kv0 + (c & 1) * 16 + srow) * EH + (c >> 1) * 32 + s16,
                  (char*)Ks + c * 1024);
      // V chunk: d rows [c*16, c*16+16)
      gload_lds16(Vbase + (size_t)(c * 16 + srow) * SEQ + kv0 + s16,
                  (char*)Vs + c * 1024);
    }
    asm volatile("s_waitcnt vmcnt(0)" ::: "memory");
    __syncthreads();

    // ---- S = Q K^T (16 MFMA; kf reads are contiguous-1KB per wave) ----
    f32x4 sf[2] = {};
    __builtin_amdgcn_s_setprio(1);
#pragma unroll
    for (int nt = 0; nt < 2; nt++)
#pragma unroll
      for (int kst = 0; kst < 8; kst++) {
        bf16x8 kf = *(const bf16x8*)&Ks[kst * 1024 + (nt * 16 + l15) * 32 + 8 * l4];
        sf[nt] = __builtin_amdgcn_mfma_f32_16x16x32_bf16(qf[kst], kf, sf[nt], 0, 0, 0);
      }
    __builtin_amdgcn_s_setprio(0);

    // ---- online softmax (exp2 domain, Q pre-scaled, distributed l) ----
    const bool maskt = (t >= 2 * qt);   // only the 2 diagonal tiles mask
    float pp[2][4];
    float fsc[4];
    bool skip[4];
#pragma unroll
    for (int r = 0; r < 4; r++) {
      float sc[2];
      float mx = -1e30f;
#pragma unroll
      for (int nt = 0; nt < 2; nt++) {
        float s = sf[nt][r];
        if (maskt) {
          const int qrow = q0 + w * 16 + 4 * l4 + r;
          s += (kv0 + nt * 16 + l15 > qrow) ? kMaskL2 : 0.0f;
        }
        sc[nt] = s;
        mx = fmaxf(mx, s);
      }
      mx = fmaxf(mx, __shfl_xor(mx, 1));
      mx = fmaxf(mx, __shfl_xor(mx, 2));
      mx = fmaxf(mx, __shfl_xor(mx, 4));
      mx = fmaxf(mx, __shfl_xor(mx, 8));
      skip[r] = __all(mx <= mst[r] + kThrL2);
      float mref;
      if (skip[r]) {
        fsc[r] = 1.0f;
        mref = mst[r];
      } else {
        float mnew = fmaxf(mst[r], mx);
        fsc[r] = exp2f(mst[r] - mnew);
        mst[r] = mnew;
        mref = mnew;
      }
      float rs = 0.f;
#pragma unroll
      for (int nt = 0; nt < 2; nt++) {
        float e = exp2f(sc[nt] - mref);
        pp[nt][r] = e;
        rs += e;
      }
      lst[r] = lst[r] * fsc[r] + rs;   // per-lane partial; reduced at the end
    }
#pragma unroll
    for (int r = 0; r < 4; r++) {
      if (!skip[r]) {
#pragma unroll
        for (int nt = 0; nt < 16; nt++) o[nt][r] *= fsc[r];
      }
    }

    // ---- P -> per-wave LDS [16][32] (wave-local, no barrier needed) ----
#pragma unroll
    for (int nt = 0; nt < 2; nt++)
#pragma unroll
      for (int r = 0; r < 4; r++)
        Ps[w * 512 + (4 * l4 + r) * 32 + nt * 16 + l15] = f2bf(pp[nt][r]);

    // ---- O += P V (16 MFMA) ----
    __builtin_amdgcn_s_setprio(1);
    bf16x8 af = *(const bf16x8*)&Ps[w * 512 + l15 * 32 + 8 * l4];
#pragma unroll
    for (int nt = 0; nt < 16; nt++) {
      bf16x8 vf = *(const bf16x8*)&Vs[(nt * 16 + l15) * 32 + 8 * l4];
      o[nt] = __builtin_amdgcn_mfma_f32_16x16x32_bf16(af, vf, o[nt], 0, 0, 0);
    }
    __builtin_amdgcn_s_setprio(0);
    __syncthreads();   // all reads done before next stage overwrites
  }

  // ---- reduce distributed l, normalize, store ctx ----
  float inv[4];
#pragma unroll
  for (int r = 0; r < 4; r++) {
    float rs = lst[r];
    rs += __shfl_xor(rs, 1);
    rs += __shfl_xor(rs, 2);
    rs += __shfl_xor(rs, 4);
    rs += __shfl_xor(rs, 8);
    inv[r] = 1.f / rs;
  }
  const int mrow = b * SEQ + q0 + w * 16 + 4 * l4;
#pragma unroll
  for (int nt = 0; nt < 16; nt++) {
    const int d = h * EMB + nt * 16 + l15;
#pragma unroll
    for (int r = 0; r < 4; r++)
      Ctx[(size_t)(mrow + r) * EH + d] = f2bf(o[nt][r] * inv[r]);
  }
}

extern "C" void kernel_launch(void* const* d_in, const int* in_sizes, int n_in,
                              void* d_out, int out_size, void* d_ws, size_t ws_size,
                              hipStream_t stream) {
  const float* x   = (const float*)d_in[0];
  const float* Wq  = (const float*)d_in[2];
  const float* bq  = (const float*)d_in[3];
  const float* Wk  = (const float*)d_in[4];
  const float* bk  = (const float*)d_in[5];
  const float* Wv  = (const float*)d_in[6];
  const float* bv  = (const float*)d_in[7];
  const float* Wfc = (const float*)d_in[8];
  const float* bfc = (const float*)d_in[9];
  float* out = (float*)d_out;

  short* ws    = (short*)d_ws;
  short* xb    = ws;                  // 4096*256
  short* wqkvt = xb + 1048576;        // 3*3072*256 contiguous [9216][256]
  short* wfct  = wqkvt + 3 * 786432;  // 256*3072
  short* q     = wfct + 786432;       // 4096*3072 (pre-scaled by log2e/16)
  short* k     = q + 12582912;
  short* vt    = k + 12582912;        // [b][h][d][s]
  short* ctx   = vt + 12582912;       // 4096*3072

  cast_x_kernel<<<1024, 256, 0, stream>>>(x, xb);
  transpose_qkv_kernel<<<dim3(EH / 32, EMB / 32, 3), 256, 0, stream>>>(Wq, Wk, Wv, wqkvt);
  transpose_cast_kernel<<<dim3(EMB / 32, EH / 32), 256, 0, stream>>>(Wfc, wfct, EH, EMB);

  qkv_gemm_kernel<<<dim3(MROWS / 128, 9216 / 128), 256, 0, stream>>>(
      xb, wqkvt, bq, bk, bv, q, k, vt);

  attn_kernel<<<dim3(BATCH * NH, SEQ / 64), 256, 0, stream>>>(q, k, vt, ctx);

  fc_gemm_kernel<<<dim3(MROWS / 64, EMB / 64), 256, 0, stream>>>(ctx, wfct, bfc, out, MROWS, EMB, EH);
}